// Round 5
// baseline (108.076 us; speedup 1.0000x reference)
//
#include <hip/hip_runtime.h>

typedef short bf16x8 __attribute__((ext_vector_type(8)));
typedef unsigned short u16;
typedef u16 u16x8 __attribute__((ext_vector_type(8)));
typedef u16 u16x4 __attribute__((ext_vector_type(4)));
typedef float f32x4 __attribute__((ext_vector_type(4)));

constexpr int TPB  = 256;
constexpr int RPB  = 64;    // rows per block
constexpr int DIM  = 300;   // embedding dim
constexpr int KPAD = 320;   // padded K (10 x 32)
constexpr int NKT  = 10;    // K-steps of 32
constexpr int H1N  = 64;
constexpr int NA   = 18;
constexpr int NK   = 32;
constexpr int NC   = 384;
constexpr float LOG_HALF = -0.6931471805599453f;

__device__ __forceinline__ float fast_sigmoid(float z) {
    return __builtin_amdgcn_rcpf(1.0f + __expf(-z));
}
__device__ __forceinline__ float lsig(float z) {           // stable log(sigmoid(z))
    return fminf(z, 0.0f) - __logf(1.0f + __expf(-fabsf(z)));
}
__device__ __forceinline__ u16 f2bf(float f) {             // f32 -> bf16 RNE
    unsigned u = __builtin_bit_cast(unsigned, f);
    return (u16)((u + 0x7FFFu + ((u >> 16) & 1u)) >> 16);
}
__device__ __forceinline__ float bf2f(u16 h) {
    return __builtin_bit_cast(float, ((unsigned)h) << 16);
}
// spread 8 bits to 8 nibbles (bit a -> bit 4a)
__device__ __forceinline__ unsigned spread8(unsigned v) {
    v = (v | (v << 12)) & 0x000F000Fu;
    v = (v | (v << 6))  & 0x03030303u;
    v = (v | (v << 3))  & 0x11111111u;
    return v;
}

// prep: W1 -> bf16 W1^T padded [64][320]; codebook -> 18-bit masks
__global__ __launch_bounds__(384)
void prep_k(const float* __restrict__ W1, const float* __restrict__ cbf,
            u16* __restrict__ w1t, unsigned* __restrict__ cbw)
{
    const int c = blockIdx.x;
    const int t = threadIdx.x;
    if (c < 64) {
        if (t < KPAD) {
            const float w = (t < DIM) ? W1[t * H1N + c] : 0.0f;
            w1t[c * KPAD + t] = f2bf(w);
        }
    } else {
        if (t < NC) {
            unsigned bits = 0u;
            #pragma unroll
            for (int a = 0; a < NA; ++a)
                bits |= (cbf[t * NA + a] != 0.0f) ? (1u << a) : 0u;
            cbw[t] = bits;
        }
    }
}

__global__ __launch_bounds__(TPB, 4)
void fused_mf2(const float* __restrict__ x, const float* __restrict__ y,
               const float* __restrict__ ob, const float* __restrict__ b1,
               const float* __restrict__ W2, const float* __restrict__ b2,
               const float* __restrict__ W3, const float* __restrict__ b3,
               const int* __restrict__ neg_idx,
               const u16* __restrict__ w1t, const unsigned* __restrict__ cbw,
               float* __restrict__ out_wu, float2* __restrict__ blk_part)
{
    __shared__ u16 xs[RPB * KPAD];                 // 40960 B == whole LDS budget
    u16*      h1s     = xs;                        // [64][64] bf16, bytes 0..8191
    unsigned* cb_bits = (unsigned*)(xs + 4096);    // bytes 8192..9727
    float*    wsum    = (float*)(xs + 4864);       // bytes 9728..9743
    int*      wcnt    = (int*)(xs + 4872);         // bytes 9744..9759

    const int tid  = threadIdx.x;
    const int lane = tid & 63;
    const int wv   = tid >> 6;
    const int rh   = wv >> 1;          // row half
    const int chh  = wv & 1;           // col half
    const int kg   = (lane >> 4) * 8;  // k-group in K=32 step
    const int l15  = lane & 15;
    const long brow = (long)blockIdx.x * RPB;
    const float* xg = x + brow * DIM;

    // ---- stage x f32 -> bf16 swizzled LDS: 19 independent float4 loads ----
    #pragma unroll
    for (int ch = 0; ch < 19; ++ch) {
        const int f = ch * TPB + tid;              // float4 index, 4800 total
        if (ch < 18 || f < 4800) {
            const float4 v = *(const float4*)(xg + f * 4);
            const int row = f / 75, k = (f - row * 75) * 4;
            const int kk = k ^ ((row & 7) << 3);   // in-row XOR swizzle (bijective)
            u16x4 pk = { f2bf(v.x), f2bf(v.y), f2bf(v.z), f2bf(v.w) };
            *(u16x4*)(xs + row * KPAD + kk) = pk;
        }
    }
    // zero-pad k in [300,320)
    #pragma unroll
    for (int uu = 0; uu < 5; ++uu) {
        const int e = uu * TPB + tid;              // 0..1279
        const int row = e / 20, kp = e - row * 20;
        xs[row * KPAD + ((DIM + kp) ^ ((row & 7) << 3))] = 0;
    }

    // ---- B-frags: 20 vector loads from pre-transposed bf16 W1T (L2-hot) ----
    bf16x8 bfr[2][NKT];                            // 80 VGPR
    #pragma unroll
    for (int ct = 0; ct < 2; ++ct) {
        const int col = chh * 32 + ct * 16 + l15;
        const u16* wp = w1t + col * KPAD + kg;
        #pragma unroll
        for (int kt = 0; kt < NKT; ++kt)
            bfr[ct][kt] = *(const bf16x8*)(wp + kt * 32);
    }

    // ---- early-issue downstream loads (fly during MFMA phase) ----
    const int rloc = wv * 16 + (lane >> 2);
    const int p    = lane & 3;
    const long bds = brow + rloc;
    const int4* nb = (const int4*)(neg_idx + bds * NK + p * 8);
    const int4 n0 = nb[0], n1 = nb[1];
    const float* obr = ob + bds * NA + p * 4;
    const float2 oA = *(const float2*)obr, oB = *(const float2*)(obr + 2);
    const float  oT = (p < 2) ? ob[bds * NA + 16 + p] : 0.f;
    const float* yr = y + bds * NA + p * 4;
    const float2 yA = *(const float2*)yr, yB = *(const float2*)(yr + 2);
    const float  yT = (p < 2) ? y[bds * NA + 16 + p] : 0.f;
    const unsigned cbv0 = cbw[tid];
    const unsigned cbv1 = (tid < NC - TPB) ? cbw[tid + TPB] : 0u;

    __syncthreads();                               // b1: x tile ready

    // ---- MFMA: A from LDS (b128, swizzled), B in regs ----
    f32x4 acc[2][2];
    #pragma unroll
    for (int rt = 0; rt < 2; ++rt)
        #pragma unroll
        for (int ct = 0; ct < 2; ++ct)
            acc[rt][ct] = (f32x4){0.f, 0.f, 0.f, 0.f};
    #pragma unroll
    for (int kt = 0; kt < NKT; ++kt) {
        bf16x8 afr[2];
        #pragma unroll
        for (int rt = 0; rt < 2; ++rt) {
            const int row = rh * 32 + rt * 16 + l15;
            const int kk = (kt * 32 + kg) ^ ((row & 7) << 3);
            afr[rt] = *(const bf16x8*)(xs + row * KPAD + kk);
        }
        #pragma unroll
        for (int rt = 0; rt < 2; ++rt)
            #pragma unroll
            for (int ct = 0; ct < 2; ++ct)
                acc[rt][ct] = __builtin_amdgcn_mfma_f32_16x16x32_bf16(
                    afr[rt], bfr[ct][kt], acc[rt][ct], 0, 0, 0);
    }
    __syncthreads();                               // b2: all xs reads done

    // ---- epilogue: bias+sigmoid -> h1s (union over xs); cb_bits -> LDS ----
    const float b1v0 = b1[chh * 32 + l15];
    const float b1v1 = b1[chh * 32 + 16 + l15];
    #pragma unroll
    for (int rt = 0; rt < 2; ++rt) {
        #pragma unroll
        for (int ct = 0; ct < 2; ++ct) {
            const int col = chh * 32 + ct * 16 + l15;
            const float bv = ct ? b1v1 : b1v0;
            #pragma unroll
            for (int j = 0; j < 4; ++j) {
                const int row = rh * 32 + rt * 16 + (lane >> 4) * 4 + j;  // C/D map
                h1s[(row * H1N + col) ^ ((row & 7) << 3)] =
                    f2bf(fast_sigmoid(acc[rt][ct][j] + bv));
            }
        }
    }
    cb_bits[tid] = cbv0;
    if (tid < NC - TPB) cb_bits[tid + TPB] = cbv1;
    __syncthreads();                               // b3: h1s + cb ready

    // ================= downstream: 4 lanes per row =================
    u16x8 h1r[8];
    #pragma unroll
    for (int q = 0; q < 8; ++q)
        h1r[q] = *(const u16x8*)(h1s + ((rloc * H1N + q * 8) ^ ((rloc & 7) << 3)));

    // ---- h1 @ W2 : part p owns cols p*8..p*8+7 ----
    const float4 b2a = *(const float4*)(b2 + p * 8);
    const float4 b2b = *(const float4*)(b2 + p * 8 + 4);
    float acc2[8] = {b2a.x, b2a.y, b2a.z, b2a.w, b2b.x, b2b.y, b2b.z, b2b.w};
    #pragma unroll
    for (int i = 0; i < H1N; ++i) {
        const float hv = bf2f((u16)h1r[i >> 3][i & 7]);
        const float4 wa = *(const float4*)(W2 + i * 32 + p * 8);
        const float4 wb = *(const float4*)(W2 + i * 32 + p * 8 + 4);
        acc2[0] = fmaf(hv, wa.x, acc2[0]);
        acc2[1] = fmaf(hv, wa.y, acc2[1]);
        acc2[2] = fmaf(hv, wa.z, acc2[2]);
        acc2[3] = fmaf(hv, wa.w, acc2[3]);
        acc2[4] = fmaf(hv, wb.x, acc2[4]);
        acc2[5] = fmaf(hv, wb.y, acc2[5]);
        acc2[6] = fmaf(hv, wb.z, acc2[6]);
        acc2[7] = fmaf(hv, wb.w, acc2[7]);
    }
    float h2[8];
    #pragma unroll
    for (int j = 0; j < 8; ++j) h2[j] = fast_sigmoid(acc2[j]);

    // ---- h2 @ W3 : i-split, reduce over parts ----
    float wu[NA];
    #pragma unroll
    for (int a = 0; a < NA; ++a) wu[a] = 0.0f;
    #pragma unroll
    for (int uI = 0; uI < 8; ++uI) {
        const float hv = h2[uI];
        const float* w3r = W3 + (p * 8 + uI) * NA;
        #pragma unroll
        for (int a = 0; a < NA; ++a) wu[a] = fmaf(hv, w3r[a], wu[a]);
    }
    #pragma unroll
    for (int a = 0; a < NA; ++a) {
        wu[a] += __shfl_xor(wu[a], 1);
        wu[a] += __shfl_xor(wu[a], 2);
        wu[a] += b3[a];
    }

    float wA0, wA1, wA2, wA3, wT;
    if (p == 0)      { wA0=wu[0];  wA1=wu[1];  wA2=wu[2];  wA3=wu[3];  wT=wu[16]; }
    else if (p == 1) { wA0=wu[4];  wA1=wu[5];  wA2=wu[6];  wA3=wu[7];  wT=wu[17]; }
    else if (p == 2) { wA0=wu[8];  wA1=wu[9];  wA2=wu[10]; wA3=wu[11]; wT=0.f; }
    else             { wA0=wu[12]; wA1=wu[13]; wA2=wu[14]; wA3=wu[15]; wT=0.f; }

    float* ow = out_wu + bds * NA + p * 4;
    *(float2*)ow       = make_float2(wA0, wA1);
    *(float2*)(ow + 2) = make_float2(wA2, wA3);
    if (p < 2) out_wu[bds * NA + 16 + p] = wT;

    const float wcv[4] = {wA0 * oA.x, wA1 * oA.y, wA2 * oB.x, wA3 * oB.y};
    const float yvv[4] = {yA.x, yA.y, yB.x, yB.y};
    const float wcT = wT * oT;
    float ssum = wcv[0] + wcv[1] + wcv[2] + wcv[3] + wcT;
    ssum += __shfl_xor(ssum, 1);
    ssum += __shfl_xor(ssum, 2);
    const int mask = (ssum != 0.0f) ? 1 : 0;

    // ---- negatives: nibble-packed per-attr counts over this part's 8 negs ----
    const int ids[8] = {n0.x, n0.y, n0.z, n0.w, n1.x, n1.y, n1.z, n1.w};
    unsigned c0 = 0u, c1 = 0u, c2 = 0u;
    #pragma unroll
    for (int kk = 0; kk < 8; ++kk) {
        const unsigned bits = cb_bits[ids[kk]];
        c0 += spread8(bits & 0xFFu);
        c1 += spread8((bits >> 8) & 0xFFu);
        const unsigned t = (bits >> 16) & 3u;
        c2 += (t | (t << 3)) & 0x11u;
    }
    unsigned e0 = c0 & 0x0F0F0F0Fu;
    unsigned e1 = (c0 >> 4) & 0x0F0F0F0Fu;
    unsigned e2 = c1 & 0x0F0F0F0Fu;
    unsigned e3 = (c1 >> 4) & 0x0F0F0F0Fu;
    unsigned e4 = (c2 & 15u) | (((c2 >> 4) & 15u) << 8);
    e0 += __shfl_xor((int)e0, 1); e0 += __shfl_xor((int)e0, 2);
    e1 += __shfl_xor((int)e1, 1); e1 += __shfl_xor((int)e1, 2);
    e2 += __shfl_xor((int)e2, 1); e2 += __shfl_xor((int)e2, 2);
    e3 += __shfl_xor((int)e3, 1); e3 += __shfl_xor((int)e3, 2);
    e4 += __shfl_xor((int)e4, 1); e4 += __shfl_xor((int)e4, 2);

    float rsum = 0.0f;
    #pragma unroll
    for (int i = 0; i < 4; ++i) {
        const unsigned regE = ((i & 1) == 0) ? ((p < 2) ? e0 : e2)
                                             : ((p < 2) ? e1 : e3);
        const int sh = (((p & 1) * 2) + (i >> 1)) * 8;
        const int cn = (int)((regE >> sh) & 0xFFu);
        const float w = wcv[i];
        const float pos = (yvv[i] != 0.0f) ? lsig(w) : LOG_HALF;
        rsum += pos + (float)cn * lsig(-w) + (float)(NK - cn) * LOG_HALF;
    }
    if (p < 2) {
        const int cn = (int)((e4 >> (p * 8)) & 0xFFu);
        const float pos = (yT != 0.0f) ? lsig(wcT) : LOG_HALF;
        rsum += pos + (float)cn * lsig(-wcT) + (float)(NK - cn) * LOG_HALF;
    }
    rsum += __shfl_xor(rsum, 1);
    rsum += __shfl_xor(rsum, 2);

    // ---- block partials (no atomics) ----
    float v = (p == 0 && mask) ? rsum : 0.0f;
    int   m = (p == 0) ? mask : 0;
    #pragma unroll
    for (int off = 32; off > 0; off >>= 1) {
        v += __shfl_down(v, off);
        m += __shfl_down(m, off);
    }
    if (lane == 0) { wsum[wv] = v; wcnt[wv] = m; }
    __syncthreads();
    if (tid == 0) {
        const float s = wsum[0] + wsum[1] + wsum[2] + wsum[3];
        const int   c = wcnt[0] + wcnt[1] + wcnt[2] + wcnt[3];
        blk_part[blockIdx.x] = make_float2(s, (float)c);
    }
}

__global__ void finalize_k(const float2* __restrict__ part, int nblk,
                           float* __restrict__ out_loss) {
    __shared__ float ss[4], sc[4];
    float s = 0.f, c = 0.f;
    for (int i = threadIdx.x; i < nblk; i += 256) {
        const float2 v = part[i];
        s += v.x; c += v.y;
    }
    #pragma unroll
    for (int off = 32; off > 0; off >>= 1) {
        s += __shfl_down(s, off);
        c += __shfl_down(c, off);
    }
    const int wv = threadIdx.x >> 6;
    if ((threadIdx.x & 63) == 0) { ss[wv] = s; sc[wv] = c; }
    __syncthreads();
    if (threadIdx.x == 0) {
        const float S = ss[0] + ss[1] + ss[2] + ss[3];
        const float C = sc[0] + sc[1] + sc[2] + sc[3];
        out_loss[0] = -S / fmaxf(C, 1.0f);
    }
}

extern "C" void kernel_launch(void* const* d_in, const int* in_sizes, int n_in,
                              void* d_out, int out_size, void* d_ws, size_t ws_size,
                              hipStream_t stream)
{
    const float* x   = (const float*)d_in[0];
    const float* y   = (const float*)d_in[1];
    const float* ob  = (const float*)d_in[2];
    const float* cb  = (const float*)d_in[3];
    const float* W1  = (const float*)d_in[4];
    const float* b1  = (const float*)d_in[5];
    const float* W2  = (const float*)d_in[6];
    const float* b2  = (const float*)d_in[7];
    const float* W3  = (const float*)d_in[8];
    const float* b3  = (const float*)d_in[9];
    const int*   neg = (const int*)d_in[10];

    const int B = in_sizes[0] / DIM;        // 131072
    const int nblk = B / RPB;               // 2048

    float*    out_wu = (float*)d_out;
    u16*      w1t  = (u16*)d_ws;                          // 40960 B
    unsigned* cbw  = (unsigned*)((char*)d_ws + 40960);    // 1536 B
    float2*   part = (float2*)((char*)d_ws + 43008);      // 16 KiB

    prep_k<<<65, 384, 0, stream>>>(W1, cb, w1t, cbw);
    fused_mf2<<<nblk, TPB, 0, stream>>>(x, y, ob, b1, W2, b2, W3, b3,
                                        neg, w1t, cbw, out_wu, part);
    finalize_k<<<1, TPB, 0, stream>>>(part, nblk, out_wu + (long)B * NA);
}

// Round 6
// 51.813 us; speedup vs baseline: 2.0859x; 2.0859x over previous
//
#include <hip/hip_runtime.h>

typedef short bf16x8 __attribute__((ext_vector_type(8)));
typedef unsigned short u16;
typedef u16 u16x4 __attribute__((ext_vector_type(4)));
typedef float f32x4 __attribute__((ext_vector_type(4)));

constexpr int TPB  = 256;
constexpr int RPB  = 64;    // rows per block
constexpr int DIM  = 300;   // embedding dim
constexpr int KPAD = 320;   // padded K (10 x 32)
constexpr int NKT  = 10;    // K-steps of 32
constexpr int H1N  = 64;
constexpr int H2N  = 32;
constexpr int NA   = 18;
constexpr int NK   = 32;
constexpr int NC   = 384;
constexpr float LOG_HALF = -0.6931471805599453f;

__device__ __forceinline__ float fast_sigmoid(float z) {
    return __builtin_amdgcn_rcpf(1.0f + __expf(-z));
}
__device__ __forceinline__ float lsig(float z) {           // stable log(sigmoid(z))
    return fminf(z, 0.0f) - __logf(1.0f + __expf(-fabsf(z)));
}
__device__ __forceinline__ u16 f2bf(float f) {             // f32 -> bf16 RNE
    unsigned u = __builtin_bit_cast(unsigned, f);
    return (u16)((u + 0x7FFFu + ((u >> 16) & 1u)) >> 16);
}
// spread 8 bits to 8 nibbles (bit a -> bit 4a)
__device__ __forceinline__ unsigned spread8(unsigned v) {
    v = (v | (v << 12)) & 0x000F000Fu;
    v = (v | (v << 6))  & 0x03030303u;
    v = (v | (v << 3))  & 0x11111111u;
    return v;
}

// prep: W1->bf16 W1T[64][320], W2->bf16 W2T[32][64], W3->bf16 W3T[32][32] (cols>=18 zero),
//       codebook -> 18-bit masks
__global__ __launch_bounds__(384)
void prep_k(const float* __restrict__ W1, const float* __restrict__ W2,
            const float* __restrict__ W3, const float* __restrict__ cbf,
            u16* __restrict__ w1t, u16* __restrict__ w2t, u16* __restrict__ w3t,
            unsigned* __restrict__ cbw)
{
    const int c = blockIdx.x;
    const int t = threadIdx.x;
    if (c < 64) {
        if (t < KPAD)
            w1t[c * KPAD + t] = f2bf((t < DIM) ? W1[t * H1N + c] : 0.0f);
    } else if (c == 64) {
        if (t < NC) {
            unsigned bits = 0u;
            #pragma unroll
            for (int a = 0; a < NA; ++a)
                bits |= (cbf[t * NA + a] != 0.0f) ? (1u << a) : 0u;
            cbw[t] = bits;
        }
    } else if (c == 65) {
        for (int e = t; e < H2N * H1N; e += 384) {       // w2t[n][k] = W2[k][n]
            const int n = e >> 6, k = e & 63;
            w2t[e] = f2bf(W2[k * H2N + n]);
        }
    } else {
        for (int e = t; e < H2N * H2N; e += 384) {       // w3t[n][k] = W3[k][n], n>=18 -> 0
            const int n = e >> 5, k = e & 31;
            w3t[e] = f2bf((n < NA) ? W3[k * NA + n] : 0.0f);
        }
    }
}

__global__ __launch_bounds__(TPB, 4)
void fused_mf2(const float* __restrict__ x, const float* __restrict__ y,
               const float* __restrict__ ob, const float* __restrict__ b1,
               const float* __restrict__ b2, const float* __restrict__ b3,
               const int* __restrict__ neg_idx,
               const u16* __restrict__ w1t, const u16* __restrict__ w2t,
               const u16* __restrict__ w3t, const unsigned* __restrict__ cbw,
               float* __restrict__ out_wu, float2* __restrict__ blk_part)
{
    __shared__ __align__(16) unsigned char smem[40960];
    u16*      xs      = (u16*)smem;                 // [64][320] bf16, phase 1 only
    u16*      h1s     = (u16*)smem;                 // [64][64]  bf16, bytes 0..8191
    u16*      h2s     = (u16*)(smem + 8192);        // [64][32]  bf16, 4 KiB
    float*    wus     = (float*)(smem + 12288);     // [64][20]  f32,  5120 B
    unsigned* cb_bits = (unsigned*)(smem + 17408);  // 1536 B
    float*    wsum    = (float*)(smem + 18944);
    int*      wcnt    = (int*)(smem + 18960);

    const int tid  = threadIdx.x;
    const int lane = tid & 63;
    const int wv   = tid >> 6;
    const int l15  = lane & 15;
    const int kg   = (lane >> 4) * 8;          // k-group within a K=32 step
    const long brow = (long)blockIdx.x * RPB;
    const float* xg = x + brow * DIM;

    // ---- stage x: 19 batched float4 loads -> one vmcnt round ----
    float4 v[19];
    #pragma unroll
    for (int ch = 0; ch < 19; ++ch) {
        const int f = ch * TPB + tid;                       // float4 index (4800 total)
        v[ch] = (ch < 18 || f < 4800) ? *(const float4*)(xg + (long)f * 4)
                                      : make_float4(0.f, 0.f, 0.f, 0.f);
    }
    __builtin_amdgcn_sched_barrier(0);
    #pragma unroll
    for (int ch = 0; ch < 19; ++ch) {
        const int f = ch * TPB + tid;
        if (ch < 18 || f < 4800) {
            const int row = f / 75, k = (f - row * 75) * 4;
            const int kk = k ^ ((row & 7) << 3);            // in-row XOR swizzle
            u16x4 pk = { f2bf(v[ch].x), f2bf(v[ch].y), f2bf(v[ch].z), f2bf(v[ch].w) };
            *(u16x4*)(xs + row * KPAD + kk) = pk;
        }
    }
    #pragma unroll
    for (int uu = 0; uu < 5; ++uu) {                        // zero-pad k in [300,320)
        const int e = uu * TPB + tid;
        const int row = e / 20, kp = e - row * 20;
        xs[row * KPAD + ((DIM + kp) ^ ((row & 7) << 3))] = 0;
    }

    // ---- W1 B-frags: wave owns one 16-col tile, 10 vector loads ----
    const int colB = wv * 16 + l15;
    bf16x8 bfr[NKT];                                        // 40 VGPR
    #pragma unroll
    for (int kt = 0; kt < NKT; ++kt)
        bfr[kt] = *(const bf16x8*)(w1t + colB * KPAD + kt * 32 + kg);

    __syncthreads();                                        // b1: xs ready

    // ---- phase 1: x @ W1 (4 row-tiles x 10 K-steps) ----
    f32x4 acc[4];
    #pragma unroll
    for (int rt = 0; rt < 4; ++rt) acc[rt] = (f32x4){0.f, 0.f, 0.f, 0.f};
    #pragma unroll
    for (int kt = 0; kt < NKT; ++kt) {
        bf16x8 afr[4];
        #pragma unroll
        for (int rt = 0; rt < 4; ++rt) {
            const int row = rt * 16 + l15;
            afr[rt] = *(const bf16x8*)(xs + ((row * KPAD + kt * 32 + kg) ^ ((row & 7) << 3)));
        }
        #pragma unroll
        for (int rt = 0; rt < 4; ++rt)
            acc[rt] = __builtin_amdgcn_mfma_f32_16x16x32_bf16(afr[rt], bfr[kt], acc[rt], 0, 0, 0);
    }
    __syncthreads();                                        // b2: xs reads done

    // ---- epilogue 1: bias+sigmoid -> h1s (swizzled, aliases xs) ----
    const float b1v = b1[colB];
    #pragma unroll
    for (int rt = 0; rt < 4; ++rt) {
        #pragma unroll
        for (int j = 0; j < 4; ++j) {
            const int row = rt * 16 + (lane >> 4) * 4 + j;  // C/D map (m89)
            h1s[(row * H1N + colB) ^ ((row & 7) << 3)] = f2bf(fast_sigmoid(acc[rt][j] + b1v));
        }
    }
    cb_bits[tid] = cbw[tid];
    if (tid < NC - TPB) cb_bits[tid + TPB] = cbw[tid + TPB];

    // ---- early-issue loss inputs (fly under phases 2-3) ----
    const int rloc = wv * 16 + (lane >> 2);
    const int p    = lane & 3;
    const long bds = brow + rloc;
    const int4* nbp = (const int4*)(neg_idx + bds * NK + p * 8);
    const int4 n0 = nbp[0], n1 = nbp[1];
    const float* obr = ob + bds * NA + p * 4;
    const float2 oA = *(const float2*)obr, oB = *(const float2*)(obr + 2);
    const float  oT = (p < 2) ? ob[bds * NA + 16 + p] : 0.f;
    const float* yr = y + bds * NA + p * 4;
    const float2 yA = *(const float2*)yr, yB = *(const float2*)(yr + 2);
    const float  yT = (p < 2) ? y[bds * NA + 16 + p] : 0.f;

    __syncthreads();                                        // b3: h1s ready

    // ---- phase 2: h1 @ W2 via MFMA (wave owns rows 16wv..16wv+15) ----
    const int rowA = wv * 16 + l15;
    bf16x8 a2[2];
    #pragma unroll
    for (int kt = 0; kt < 2; ++kt)
        a2[kt] = *(const bf16x8*)(h1s + ((rowA * H1N + kt * 32 + kg) ^ ((rowA & 7) << 3)));
    f32x4 acc2[2];
    #pragma unroll
    for (int ct = 0; ct < 2; ++ct) {
        const float bb = b2[ct * 16 + l15];
        acc2[ct] = (f32x4){bb, bb, bb, bb};
    }
    #pragma unroll
    for (int ct = 0; ct < 2; ++ct)
        #pragma unroll
        for (int kt = 0; kt < 2; ++kt) {
            const bf16x8 bfr2 = *(const bf16x8*)(w2t + (ct * 16 + l15) * H1N + kt * 32 + kg);
            acc2[ct] = __builtin_amdgcn_mfma_f32_16x16x32_bf16(a2[kt], bfr2, acc2[ct], 0, 0, 0);
        }
    #pragma unroll
    for (int ct = 0; ct < 2; ++ct) {
        #pragma unroll
        for (int j = 0; j < 4; ++j) {
            const int row = wv * 16 + (lane >> 4) * 4 + j;
            const int col = ct * 16 + l15;
            h2s[(row * H2N + col) ^ ((row & 3) << 3)] = f2bf(fast_sigmoid(acc2[ct][j]));
        }
    }

    // ---- phase 3: h2 @ W3 (same-wave rows; lgkmcnt orders h2s write->read) ----
    const bf16x8 a3 = *(const bf16x8*)(h2s + ((rowA * H2N + kg) ^ ((rowA & 3) << 3)));
    f32x4 acc3[2];
    #pragma unroll
    for (int ct = 0; ct < 2; ++ct) {
        const int col = ct * 16 + l15;
        const float bb = (col < NA) ? b3[col] : 0.f;
        acc3[ct] = (f32x4){bb, bb, bb, bb};
    }
    #pragma unroll
    for (int ct = 0; ct < 2; ++ct) {
        const bf16x8 bfr3 = *(const bf16x8*)(w3t + (ct * 16 + l15) * H2N + kg);
        acc3[ct] = __builtin_amdgcn_mfma_f32_16x16x32_bf16(a3, bfr3, acc3[ct], 0, 0, 0);
    }
    // wu -> wus LDS [64][20] f32 (own-wave rows)
    #pragma unroll
    for (int j = 0; j < 4; ++j) {
        const int row = wv * 16 + (lane >> 4) * 4 + j;
        wus[row * 20 + l15] = acc3[0][j];
        if (l15 < 2) wus[row * 20 + 16 + l15] = acc3[1][j];
    }
    __builtin_amdgcn_sched_barrier(0);                      // keep reads after writes

    // ---- loss: 4 lanes/row, reading own-wave wus rows ----
    const float4 wA = *(const float4*)(wus + rloc * 20 + p * 4);
    const float  wT = (p < 2) ? wus[rloc * 20 + 16 + p] : 0.f;

    const float wcv[4] = {wA.x * oA.x, wA.y * oA.y, wA.z * oB.x, wA.w * oB.y};
    const float yvv[4] = {yA.x, yA.y, yB.x, yB.y};
    const float wcT = wT * oT;
    float ssum = wcv[0] + wcv[1] + wcv[2] + wcv[3] + wcT;
    ssum += __shfl_xor(ssum, 1);
    ssum += __shfl_xor(ssum, 2);
    const int mask = (ssum != 0.0f) ? 1 : 0;

    const int ids[8] = {n0.x, n0.y, n0.z, n0.w, n1.x, n1.y, n1.z, n1.w};
    unsigned c0 = 0u, c1 = 0u, c2 = 0u;
    #pragma unroll
    for (int kk = 0; kk < 8; ++kk) {
        const unsigned bits = cb_bits[ids[kk]];
        c0 += spread8(bits & 0xFFu);
        c1 += spread8((bits >> 8) & 0xFFu);
        const unsigned t = (bits >> 16) & 3u;
        c2 += (t | (t << 3)) & 0x11u;
    }
    unsigned e0 = c0 & 0x0F0F0F0Fu;
    unsigned e1 = (c0 >> 4) & 0x0F0F0F0Fu;
    unsigned e2 = c1 & 0x0F0F0F0Fu;
    unsigned e3 = (c1 >> 4) & 0x0F0F0F0Fu;
    unsigned e4 = (c2 & 15u) | (((c2 >> 4) & 15u) << 8);
    e0 += __shfl_xor((int)e0, 1); e0 += __shfl_xor((int)e0, 2);
    e1 += __shfl_xor((int)e1, 1); e1 += __shfl_xor((int)e1, 2);
    e2 += __shfl_xor((int)e2, 1); e2 += __shfl_xor((int)e2, 2);
    e3 += __shfl_xor((int)e3, 1); e3 += __shfl_xor((int)e3, 2);
    e4 += __shfl_xor((int)e4, 1); e4 += __shfl_xor((int)e4, 2);

    float rsum = 0.0f;
    #pragma unroll
    for (int i = 0; i < 4; ++i) {
        const unsigned regE = ((i & 1) == 0) ? ((p < 2) ? e0 : e2)
                                             : ((p < 2) ? e1 : e3);
        const int sh = (((p & 1) * 2) + (i >> 1)) * 8;
        const int cn = (int)((regE >> sh) & 0xFFu);
        const float w = wcv[i];
        const float pos = (yvv[i] != 0.0f) ? lsig(w) : LOG_HALF;
        rsum += pos + (float)cn * lsig(-w) + (float)(NK - cn) * LOG_HALF;
    }
    if (p < 2) {
        const int cn = (int)((e4 >> (p * 8)) & 0xFFu);
        const float pos = (yT != 0.0f) ? lsig(wcT) : LOG_HALF;
        rsum += pos + (float)cn * lsig(-wcT) + (float)(NK - cn) * LOG_HALF;
    }
    rsum += __shfl_xor(rsum, 1);
    rsum += __shfl_xor(rsum, 2);

    float vv = (p == 0 && mask) ? rsum : 0.0f;
    int   mm = (p == 0) ? mask : 0;
    #pragma unroll
    for (int off = 32; off > 0; off >>= 1) {
        vv += __shfl_down(vv, off);
        mm += __shfl_down(mm, off);
    }
    if (lane == 0) { wsum[wv] = vv; wcnt[wv] = mm; }
    __syncthreads();                                        // b4: wus + wsum ready

    // ---- coalesced cooperative W_user store ----
    float* og = out_wu + brow * NA;
    #pragma unroll
    for (int g = tid; g < RPB * NA; g += TPB) {
        const int row = g / NA, col = g - row * NA;
        og[g] = wus[row * 20 + col];
    }
    if (tid == 0) {
        const float s = wsum[0] + wsum[1] + wsum[2] + wsum[3];
        const int   c = wcnt[0] + wcnt[1] + wcnt[2] + wcnt[3];
        blk_part[blockIdx.x] = make_float2(s, (float)c);
    }
}

__global__ void finalize_k(const float2* __restrict__ part, int nblk,
                           float* __restrict__ out_loss) {
    __shared__ float ss[4], sc[4];
    float s = 0.f, c = 0.f;
    for (int i = threadIdx.x; i < nblk; i += 256) {
        const float2 v = part[i];
        s += v.x; c += v.y;
    }
    #pragma unroll
    for (int off = 32; off > 0; off >>= 1) {
        s += __shfl_down(s, off);
        c += __shfl_down(c, off);
    }
    const int wv = threadIdx.x >> 6;
    if ((threadIdx.x & 63) == 0) { ss[wv] = s; sc[wv] = c; }
    __syncthreads();
    if (threadIdx.x == 0) {
        const float S = ss[0] + ss[1] + ss[2] + ss[3];
        const float C = sc[0] + sc[1] + sc[2] + sc[3];
        out_loss[0] = -S / fmaxf(C, 1.0f);
    }
}

extern "C" void kernel_launch(void* const* d_in, const int* in_sizes, int n_in,
                              void* d_out, int out_size, void* d_ws, size_t ws_size,
                              hipStream_t stream)
{
    const float* x   = (const float*)d_in[0];
    const float* y   = (const float*)d_in[1];
    const float* ob  = (const float*)d_in[2];
    const float* cb  = (const float*)d_in[3];
    const float* W1  = (const float*)d_in[4];
    const float* b1  = (const float*)d_in[5];
    const float* W2  = (const float*)d_in[6];
    const float* b2  = (const float*)d_in[7];
    const float* W3  = (const float*)d_in[8];
    const float* b3  = (const float*)d_in[9];
    const int*   neg = (const int*)d_in[10];

    const int B = in_sizes[0] / DIM;        // 131072
    const int nblk = B / RPB;               // 2048

    float*    out_wu = (float*)d_out;
    u16*      w1t  = (u16*)d_ws;                          // 40960 B
    u16*      w2t  = (u16*)((char*)d_ws + 40960);         // 4096 B
    u16*      w3t  = (u16*)((char*)d_ws + 45056);         // 2048 B
    unsigned* cbw  = (unsigned*)((char*)d_ws + 47104);    // 1536 B
    float2*   part = (float2*)((char*)d_ws + 48640);      // 16 KiB

    prep_k<<<67, 384, 0, stream>>>(W1, W2, W3, cb, w1t, w2t, w3t, cbw);
    fused_mf2<<<nblk, TPB, 0, stream>>>(x, y, ob, b1, b2, b3,
                                        neg, w1t, w2t, w3t, cbw, out_wu, part);
    finalize_k<<<1, TPB, 0, stream>>>(part, nblk, out_wu + (long)B * NA);
}